// Round 13
// baseline (416.557 us; speedup 1.0000x reference)
//
#include <hip/hip_runtime.h>
#include <hip/hip_bf16.h>

#define N_NODES 50000
#define N_EDGES 640000
#define HIDDEN 128
#define N_LAYERS 4
#define NUM_RBF 50
#define CUTOFF 4.0f
#define N_GRAPHS 64
#define TAB 8192        // nearest-neighbor table (half-step 2.44e-4)
#define PSPLIT 16       // pool blocks per graph
#define COLBITS 17      // meta packing: col in [0,2^17), gi in high bits
#define CMASK ((1u << COLBITS) - 1)
#define NBUCK 196       // row buckets (256 rows each)
#define CHUNK 4096      // edges per k_bucket block
#define PADMETA 990208  // >= N_EDGES + N_NODES*7 (max padded CSR size)
#define DUMMY ((uint)N_NODES)   // col=N_NODES (zero xl row), gi=0

// k_prep block partition
#define PB_PACKW 64      // 16384/256
#define PB_EMBED 6250    // N_NODES*32/256
#define PB_COUNT 2500    // N_EDGES/256

typedef unsigned int uint;
typedef unsigned short ushort;
typedef __attribute__((ext_vector_type(8))) short bf16x8;   // MFMA A/B frag (4 VGPRs)
typedef __attribute__((ext_vector_type(4))) float f32x4;    // MFMA C/D frag

__device__ inline ushort f2bf(float f) {   // RNE float->bf16 (finite inputs)
    uint u = __float_as_uint(f);
    uint r = (u + 0x7fffu + ((u >> 16) & 1u)) >> 16;
    return (ushort)r;
}
__device__ inline uint packbf(float lo, float hi) {
    return (uint)f2bf(lo) | ((uint)f2bf(hi) << 16);
}
__device__ inline float bflo(uint u) { return __uint_as_float(u << 16); }
__device__ inline float bfhi(uint u) { return __uint_as_float(u & 0xffff0000u); }

// ---------------------------------------------------------------------------
// Fused prep: [0,64) packw (lw+fw2), [64,6314) embed, [6314,8814) edge count,
// [8814] zero the dummy xl row. All sections independent.
__global__ __launch_bounds__(256) void k_prep(const float* __restrict__ lw,
                                              const float* __restrict__ fw2,
                                              uint4* __restrict__ pb,
                                              uint4* __restrict__ pb2,
                                              const int* __restrict__ x,
                                              const float* __restrict__ emb,
                                              ushort* __restrict__ hbf,
                                              const int* __restrict__ row,
                                              int* __restrict__ counts,
                                              ushort* __restrict__ xlb) {
    int b = blockIdx.x, t = threadIdx.x;
    if (b < PB_PACKW) {
        int idx = b * 256 + t;                  // < 16384
        int which = idx >> 13;                  // 0: lw->pb, 1: fw2->pb2
        int rem = idx & 8191;
        int lane = rem & 63;
        int kc = (rem >> 6) & 3;
        int nt = (rem >> 8) & 7;
        int layer = rem >> 11;
        int quad = lane >> 4, nl = lane & 15;
        int n = nt * 16 + nl;
        const float* w = (which ? fw2 : lw) + layer * HIDDEN * HIDDEN;
        uint r[4];
        #pragma unroll
        for (int jj = 0; jj < 4; jj++) {
            int k = kc * 32 + quad * 8 + 2 * jj;
            r[jj] = packbf(w[k * HIDDEN + n], w[(k + 1) * HIDDEN + n]);
        }
        uint4 o; o.x = r[0]; o.y = r[1]; o.z = r[2]; o.w = r[3];
        (which ? pb2 : pb)[rem] = o;
    } else if (b < PB_PACKW + PB_EMBED) {
        int idx = (b - PB_PACKW) * 256 + t;     // over N_NODES*32 float4s
        if (idx < N_NODES * 32) {
            int n = idx >> 5, q = idx & 31;
            float4 v = ((const float4*)emb)[x[n] * 32 + q];
            uint2 p;
            p.x = packbf(v.x, v.y);
            p.y = packbf(v.z, v.w);
            ((uint2*)hbf)[idx] = p;
        }
    } else if (b < PB_PACKW + PB_EMBED + PB_COUNT) {
        int e = (b - PB_PACKW - PB_EMBED) * 256 + t;
        if (e < N_EDGES) atomicAdd(&counts[row[e]], 1);
    } else {
        if (t < 64) ((uint*)(xlb + (size_t)N_NODES * HIDDEN))[t] = 0;
    }
}

// ---------------------------------------------------------------------------
// Fused table build: one block = 64 grid points of one layer.
// rbf -> stage1 (VALU, K=50) -> LDS bf16 -> stage2 MFMA -> ctab bf16 rows.
__global__ __launch_bounds__(256) void k_tab(const float* __restrict__ fw1,
                                             const float* __restrict__ fb1,
                                             const uint4* __restrict__ pb2,
                                             const float* __restrict__ fb2,
                                             ushort* __restrict__ ctab) {
    int layer = blockIdx.x / (TAB / 64);
    int g0 = (blockIdx.x % (TAB / 64)) * 64;
    int t = threadIdx.x;
    __shared__ float rbf[64][NUM_RBF];      // 12.8 KB
    __shared__ ushort hid[64][HIDDEN];      // 16 KB
    for (int idx = t; idx < 64 * NUM_RBF; idx += 256) {
        int gg = idx / NUM_RBF, r = idx % NUM_RBF;
        float d = (CUTOFF * (g0 + gg)) / (float)(TAB - 1);
        float offset = (CUTOFF * r) / (float)(NUM_RBF - 1);
        float delta = CUTOFF / (float)(NUM_RBF - 1);
        float coeff = -0.5f / (delta * delta);
        float tt = d - offset;
        rbf[gg][r] = expf(coeff * tt * tt);
    }
    __syncthreads();
    // stage 1: thread handles channel ch for 32 grid points
    {
        int ch = t & 127;
        int gb = (t >> 7) * 32;             // 0 or 32
        const float* w1 = fw1 + layer * NUM_RBF * HIDDEN;
        float b1 = fb1[layer * HIDDEN + ch];
        float acc[32];
        #pragma unroll
        for (int i = 0; i < 32; i++) acc[i] = b1;
        for (int r = 0; r < NUM_RBF; r++) {
            float w = w1[r * HIDDEN + ch];
            #pragma unroll
            for (int i = 0; i < 32; i++) acc[i] = fmaf(rbf[gb + i][r], w, acc[i]);
        }
        #pragma unroll
        for (int i = 0; i < 32; i++) hid[gb + i][ch] = f2bf(fmaxf(acc[i], 0.0f));
    }
    __syncthreads();
    // stage 2: wave w does MFMA for local rows w*16..w*16+15
    int wave = t >> 6, lane = t & 63;
    int quad = lane >> 4, ml = lane & 15;
    const ushort* arow = &hid[wave * 16 + ml][quad * 8];
    bf16x8 a[4];
    #pragma unroll
    for (int kc = 0; kc < 4; kc++) a[kc] = *(const bf16x8*)(arow + kc * 32);
    const uint4* pb = pb2 + (size_t)layer * 8 * 4 * 64;
    const float* bias = fb2 + layer * HIDDEN;
    int m0 = layer * TAB + g0 + wave * 16;
    #pragma unroll
    for (int nt = 0; nt < 8; nt++) {
        f32x4 acc = {0.f, 0.f, 0.f, 0.f};
        #pragma unroll
        for (int kc = 0; kc < 4; kc++) {
            bf16x8 bfr = *(const bf16x8*)(pb + (nt * 4 + kc) * 64 + lane);
            acc = __builtin_amdgcn_mfma_f32_16x16x32_bf16(a[kc], bfr, acc, 0, 0, 0);
        }
        int col = nt * 16 + ml;
        float bv = bias[col];
        #pragma unroll
        for (int r = 0; r < 4; r++) {
            int rowi = m0 + quad * 4 + r;
            ctab[(size_t)rowi * HIDDEN + col] = f2bf(acc[r] + bv);
        }
    }
}

// ---------------------------------------------------------------------------
// Single-block full scan: padded (x8) exclusive prefix over counts, writes
// offsets + bucket cursors + graph bounds. 49 coalesced 1024-wide tiles.
__global__ __launch_bounds__(1024) void k_scanall(const int* __restrict__ counts,
                                                  int* __restrict__ offsets,
                                                  int* __restrict__ bcur,
                                                  const int* __restrict__ batch,
                                                  int* __restrict__ gstart) {
    int t = threadIdx.x;
    int lane = t & 63, wv = t >> 6;
    __shared__ int wsum[16];
    __shared__ int carry;
    if (t == 0) carry = 0;
    __syncthreads();
    const int NT = (N_NODES + 1023) / 1024;   // 49
    for (int tile = 0; tile < NT; tile++) {
        int i = tile * 1024 + t;
        int v = (i < N_NODES) ? ((counts[i] + 7) & ~7) : 0;
        int s = v;
        #pragma unroll
        for (int off = 1; off < 64; off <<= 1) {
            int u = __shfl_up(s, off, 64);
            if (lane >= off) s += u;
        }
        if (lane == 63) wsum[wv] = s;
        __syncthreads();
        int woff = 0;
        for (int w = 0; w < wv; w++) woff += wsum[w];
        int excl = s + woff - v + carry;
        if (i < N_NODES) {
            offsets[i] = excl;
            if ((i & 255) == 0) bcur[i >> 8] = excl;
        }
        __syncthreads();
        if (t == 1023) carry = excl + v;
        __syncthreads();
    }
    if (t == 0) offsets[N_NODES] = carry;
    if (t <= N_GRAPHS) {
        int lo = 0, hi = N_NODES;
        while (lo < hi) {
            int mid = (lo + hi) >> 1;
            if (batch[mid] < t) lo = mid + 1; else hi = mid;
        }
        gstart[t] = lo;
    }
}

// ---------------------------------------------------------------------------
// Bucket sort pass: chunk of CHUNK edges -> LDS histogram/scan/stage ->
// coalesced run writes into per-bucket global spans (8B: packed meta + row).
__global__ __launch_bounds__(256) void k_bucket(const int* __restrict__ row,
                                                const int* __restrict__ col,
                                                const float* __restrict__ eattr,
                                                int* __restrict__ bcur,
                                                uint2* __restrict__ bs) {
    __shared__ uint2 stage[CHUNK];
    __shared__ int hist[256], lscan[256], lcur[256], gbase[256];
    __shared__ int wsum[4];
    int t = threadIdx.x;
    int e0 = blockIdx.x * CHUNK;
    int ne = min(CHUNK, N_EDGES - e0);
    hist[t] = 0;
    __syncthreads();
    for (int i = t; i < ne; i += 256)
        atomicAdd(&hist[row[e0 + i] >> 8], 1);
    __syncthreads();
    int v = hist[t];
    int lane = t & 63, wid = t >> 6;
    int s = v;
    #pragma unroll
    for (int off = 1; off < 64; off <<= 1) {
        int u = __shfl_up(s, off, 64);
        if (lane >= off) s += u;
    }
    if (lane == 63) wsum[wid] = s;
    __syncthreads();
    int woff = 0;
    for (int w = 0; w < wid; w++) woff += wsum[w];
    int excl = s + woff - v;
    lscan[t] = excl;
    lcur[t] = excl;
    if (v > 0) gbase[t] = atomicAdd(&bcur[t], v);   // reserve span in bucket
    __syncthreads();
    for (int i = t; i < ne; i += 256) {
        int e = e0 + i;
        int r = row[e];
        float tt = eattr[e] * ((float)(TAB - 1) / CUTOFF);
        int gi = (int)(tt + 0.5f);
        gi = min(max(gi, 0), TAB - 1);
        int pos = atomicAdd(&lcur[r >> 8], 1);
        uint2 sv;
        sv.x = (uint)col[e] | ((uint)gi << COLBITS);
        sv.y = (uint)r;
        stage[pos] = sv;
    }
    __syncthreads();
    for (int i = t; i < ne; i += 256) {
        uint2 sv = stage[i];
        int b = sv.y >> 8;
        bs[gbase[b] + (i - lscan[b])] = sv;   // coalesced run writes
    }
}

// Fine scatter within each bucket's meta window (single-writer block), then
// fill each node's pad slots [real_end, padded_end) with DUMMY edges.
__global__ __launch_bounds__(256) void k_scatter(const uint2* __restrict__ bs,
                                                 const int* __restrict__ offsets,
                                                 const int* __restrict__ bend,
                                                 uint* __restrict__ meta) {
    int b = blockIdx.x, t = threadIdx.x;
    int r0 = b << 8;
    __shared__ int cur[256];
    int rmax = min(r0 + 256, N_NODES);
    cur[t] = offsets[min(r0 + t, N_NODES)];
    __syncthreads();
    int s = offsets[r0], e = bend[b];       // real edges live in [s, bend)
    for (int i = s + t; i < e; i += 256) {
        uint2 v = bs[i];
        int slot = atomicAdd(&cur[v.y - r0], 1);
        meta[slot] = v.x;
    }
    __syncthreads();
    int node = r0 + t;
    if (node < rmax) {
        int end = offsets[node + 1];
        for (int i = cur[t]; i < end; i++) meta[i] = DUMMY;
    }
}

// ---------------------------------------------------------------------------
// xl = h @ lw + lb via bf16 MFMA. One wave = 16 rows x 128 cols.
__global__ __launch_bounds__(256) void k_xl(const ushort* __restrict__ hbf,
                                            const uint4* __restrict__ pb,
                                            const float* __restrict__ lb,
                                            ushort* __restrict__ xlb) {
    int wave = threadIdx.x >> 6, lane = threadIdx.x & 63;
    int m0 = (blockIdx.x * 4 + wave) * 16;
    if (m0 >= N_NODES) return;
    int quad = lane >> 4, ml = lane & 15;
    const ushort* arow = hbf + (size_t)(m0 + ml) * HIDDEN + quad * 8;
    bf16x8 a[4];
    #pragma unroll
    for (int kc = 0; kc < 4; kc++) a[kc] = *(const bf16x8*)(arow + kc * 32);
    #pragma unroll
    for (int nt = 0; nt < 8; nt++) {
        f32x4 acc = {0.f, 0.f, 0.f, 0.f};
        #pragma unroll
        for (int kc = 0; kc < 4; kc++) {
            bf16x8 b = *(const bf16x8*)(pb + (nt * 4 + kc) * 64 + lane);
            acc = __builtin_amdgcn_mfma_f32_16x16x32_bf16(a[kc], b, acc, 0, 0, 0);
        }
        int col = nt * 16 + ml;
        float bias = lb[col];
        #pragma unroll
        for (int r = 0; r < 4; r++) {
            int row = m0 + quad * 4 + r;
            xlb[(size_t)row * HIDDEN + col] = f2bf(acc[r] + bias);
        }
    }
}

// ---------------------------------------------------------------------------
// Aggregation + residual + LayerNorm, fused. One wave per node.
// Edge lists padded to x8; paired 8-groups keep 32 gathers in flight.
__global__ __launch_bounds__(256) void k_agg(const ushort* __restrict__ xlb,
                                             const uint* __restrict__ meta,
                                             const int* __restrict__ offsets,
                                             const uint* __restrict__ ctab,
                                             const ushort* __restrict__ hb_in,
                                             const float* __restrict__ g,
                                             const float* __restrict__ b,
                                             ushort* __restrict__ hbf_out) {
    int wid = threadIdx.x >> 6;
    int lane = threadIdx.x & 63;
    int n = blockIdx.x * 4 + wid;
    if (n >= N_NODES) return;
    const uint* xl2 = (const uint*)xlb;    // bf16 pair per uint
    float accx = 0.f, accy = 0.f;
    int p0 = offsets[n], p1 = offsets[n + 1];
    int cnt = p1 - p0;                      // multiple of 8
    for (int base = 0; base < cnt; base += 64) {
        int li = p0 + base + lane;
        uint mlv = meta[min(li, PADMETA - 1)];   // coalesced batch load
        int kk = min(64, cnt - base);            // multiple of 8
        int p = 0;
        for (; p + 16 <= kk; p += 16) {          // paired groups: 32 loads in flight
            uint wA[8], xA[8], wB[8], xB[8];
            #pragma unroll
            for (int i = 0; i < 8; i++) {
                uint m = __builtin_amdgcn_readlane(mlv, p + i);
                wA[i] = ctab[(m >> COLBITS) * 64 + lane];
                xA[i] = xl2[(m & CMASK) * 64 + lane];
            }
            #pragma unroll
            for (int i = 0; i < 8; i++) {
                uint m = __builtin_amdgcn_readlane(mlv, p + 8 + i);
                wB[i] = ctab[(m >> COLBITS) * 64 + lane];
                xB[i] = xl2[(m & CMASK) * 64 + lane];
            }
            #pragma unroll
            for (int i = 0; i < 8; i++) {
                accx = fmaf(bflo(wA[i]), bflo(xA[i]), accx);
                accy = fmaf(bfhi(wA[i]), bfhi(xA[i]), accy);
            }
            #pragma unroll
            for (int i = 0; i < 8; i++) {
                accx = fmaf(bflo(wB[i]), bflo(xB[i]), accx);
                accy = fmaf(bfhi(wB[i]), bfhi(xB[i]), accy);
            }
        }
        for (; p < kk; p += 8) {                 // at most one trailing group
            uint wA[8], xA[8];
            #pragma unroll
            for (int i = 0; i < 8; i++) {
                uint m = __builtin_amdgcn_readlane(mlv, p + i);
                wA[i] = ctab[(m >> COLBITS) * 64 + lane];
                xA[i] = xl2[(m & CMASK) * 64 + lane];
            }
            #pragma unroll
            for (int i = 0; i < 8; i++) {
                accx = fmaf(bflo(wA[i]), bflo(xA[i]), accx);
                accy = fmaf(bfhi(wA[i]), bfhi(xA[i]), accy);
            }
        }
    }
    uint hvp = ((const uint*)hb_in)[n * 64 + lane];
    float vx = bflo(hvp) + accx, vy = bfhi(hvp) + accy;
    float s = vx + vy;
    #pragma unroll
    for (int off = 32; off; off >>= 1) s += __shfl_xor(s, off, 64);
    float mu = s * (1.0f / 128.0f);
    float dx = vx - mu, dy = vy - mu;
    float s2 = dx * dx + dy * dy;
    #pragma unroll
    for (int off = 32; off; off >>= 1) s2 += __shfl_xor(s2, off, 64);
    float rstd = rsqrtf(s2 * (1.0f / 128.0f) + 1e-5f);
    float2 gv = ((const float2*)g)[lane];
    float2 bv = ((const float2*)b)[lane];
    float ox = fmaf(dx * rstd, gv.x, bv.x);
    float oy = fmaf(dy * rstd, gv.y, bv.y);
    ((uint*)hbf_out)[n * 64 + lane] = packbf(ox, oy);
}

// ---------------------------------------------------------------------------
// Mean pool, stage 1: PSPLIT blocks per graph write partial sums (bf16 input).
__global__ __launch_bounds__(256) void k_pool_part(const ushort* __restrict__ hbf,
                                                   const int* __restrict__ gstart,
                                                   float* __restrict__ partial) {
    int g = blockIdx.x / PSPLIT;
    int t = blockIdx.x % PSPLIT;
    int jp = threadIdx.x & 63;       // bf16-pair index (2 feats per thread)
    int half = threadIdx.x >> 6;     // 4 node-rows in flight
    int s = gstart[g], e = gstart[g + 1];
    float accx = 0.f, accy = 0.f;
    const uint* h2 = (const uint*)hbf;
    for (int n = s + t * 4 + half; n < e; n += PSPLIT * 4) {
        uint v = h2[n * 64 + jp];
        accx += bflo(v);
        accy += bfhi(v);
    }
    __shared__ float redx[256], redy[256];
    redx[threadIdx.x] = accx;
    redy[threadIdx.x] = accy;
    __syncthreads();
    if (half == 0) {
        float tx = redx[jp] + redx[jp + 64] + redx[jp + 128] + redx[jp + 192];
        float ty = redy[jp] + redy[jp + 64] + redy[jp + 128] + redy[jp + 192];
        float2 o; o.x = tx; o.y = ty;
        ((float2*)partial)[(g * PSPLIT + t) * 64 + jp] = o;
    }
}

// Mean pool, stage 2: reduce PSPLIT partials, divide by count.
__global__ void k_pool_fin(const float* __restrict__ partial,
                           const int* __restrict__ gstart,
                           float* __restrict__ out) {
    int idx = blockIdx.x * 128 + threadIdx.x;   // N_GRAPHS*HIDDEN total
    int g = idx >> 7, j = idx & 127;
    float tot = 0.f;
    #pragma unroll
    for (int t = 0; t < PSPLIT; t++) tot += partial[(g * PSPLIT + t) * HIDDEN + j];
    float c = (float)(gstart[g + 1] - gstart[g]);
    out[idx] = tot / fmaxf(c, 1.0f);
}

// ---------------------------------------------------------------------------
extern "C" void kernel_launch(void* const* d_in, const int* in_sizes, int n_in,
                              void* d_out, int out_size, void* d_ws, size_t ws_size,
                              hipStream_t stream) {
    const int* x = (const int*)d_in[0];
    const int* edge_index = (const int*)d_in[1];
    const int* row = edge_index;               // edge_index[0]
    const int* col = edge_index + N_EDGES;     // edge_index[1]
    const float* eattr = (const float*)d_in[2];
    const int* batch = (const int*)d_in[3];
    const float* emb = (const float*)d_in[4];
    const float* fw1 = (const float*)d_in[5];
    const float* fb1 = (const float*)d_in[6];
    const float* fw2 = (const float*)d_in[7];
    const float* fb2 = (const float*)d_in[8];
    const float* lw = (const float*)d_in[9];
    const float* lb = (const float*)d_in[10];
    const float* ln_g = (const float*)d_in[11];
    const float* ln_b = (const float*)d_in[12];
    float* out = (float*)d_out;

    char* ws = (char*)d_ws;
    size_t off = 0;
    auto alloc = [&](size_t bytes) -> void* {
        void* p = ws + off;
        off = (off + bytes + 255) & ~(size_t)255;
        return p;
    };
    uint* ctab     = (uint*)alloc((size_t)N_LAYERS * TAB * 64 * 4);
    ushort* hbf_a  = (ushort*)alloc((size_t)N_NODES * HIDDEN * 2);
    ushort* hbf_b  = (ushort*)alloc((size_t)N_NODES * HIDDEN * 2);
    ushort* xlb    = (ushort*)alloc((size_t)(N_NODES + 1) * HIDDEN * 2);  // +1 zero row
    uint4* pb      = (uint4*)alloc((size_t)N_LAYERS * 8 * 4 * 64 * 16);
    uint4* pb2     = (uint4*)alloc((size_t)N_LAYERS * 8 * 4 * 64 * 16);
    int* counts    = (int*)alloc((size_t)(N_NODES + 1) * 4);
    int* offsets   = (int*)alloc((size_t)(N_NODES + 1) * 4);
    int* bcur      = (int*)alloc(256 * 4);
    uint2* bs      = (uint2*)alloc((size_t)PADMETA * 8);
    uint* meta     = (uint*)alloc((size_t)PADMETA * 4);
    int* gstart    = (int*)alloc((size_t)(N_GRAPHS + 1) * 4);
    float* ppart   = (float*)alloc((size_t)N_GRAPHS * PSPLIT * HIDDEN * 4);

    hipMemsetAsync(counts, 0, (size_t)(N_NODES + 1) * 4, stream);

    const int PREP_GRID = PB_PACKW + PB_EMBED + PB_COUNT + 1;   // 8815
    k_prep<<<PREP_GRID, 256, 0, stream>>>(lw, fw2, pb, pb2, x, emb, hbf_a,
                                          row, counts, xlb);
    k_tab<<<N_LAYERS * (TAB / 64), 256, 0, stream>>>(fw1, fb1, pb2, fb2, (ushort*)ctab);
    k_scanall<<<1, 1024, 0, stream>>>(counts, offsets, bcur, batch, gstart);
    k_bucket<<<(N_EDGES + CHUNK - 1) / CHUNK, 256, 0, stream>>>(row, col, eattr, bcur, bs);
    k_scatter<<<NBUCK, 256, 0, stream>>>(bs, offsets, bcur, meta);

    ushort* hb_cur = hbf_a; ushort* hb_nxt = hbf_b;
    const int XLBLK = (N_NODES / 16 + 3) / 4;   // 3125 waves -> 782 blocks
    for (int i = 0; i < N_LAYERS; i++) {
        k_xl<<<XLBLK, 256, 0, stream>>>(hb_cur, pb + (size_t)i * 8 * 4 * 64,
                                        lb + i * HIDDEN, xlb);
        k_agg<<<(N_NODES + 3) / 4, 256, 0, stream>>>(xlb, meta, offsets,
                                                     ctab + (size_t)i * TAB * 64,
                                                     hb_cur, ln_g + i * HIDDEN,
                                                     ln_b + i * HIDDEN, hb_nxt);
        ushort* tb = hb_cur; hb_cur = hb_nxt; hb_nxt = tb;
    }
    k_pool_part<<<N_GRAPHS * PSPLIT, 256, 0, stream>>>(hb_cur, gstart, ppart);
    k_pool_fin<<<(N_GRAPHS * HIDDEN + 127) / 128, 128, 0, stream>>>(ppart, gstart, out);
}

// Round 14
// 370.829 us; speedup vs baseline: 1.1233x; 1.1233x over previous
//
#include <hip/hip_runtime.h>
#include <hip/hip_bf16.h>

#define N_NODES 50000
#define N_EDGES 640000
#define HIDDEN 128
#define N_LAYERS 4
#define NUM_RBF 50
#define CUTOFF 4.0f
#define N_GRAPHS 64
#define TAB 8192        // nearest-neighbor table (half-step 2.44e-4)
#define PSPLIT 16       // pool blocks per graph
#define COLBITS 17      // meta packing: col in [0,2^17), gi in high bits
#define CMASK ((1u << COLBITS) - 1)
#define NBUCK 196       // row buckets (256 rows each)
#define CHUNK 4096      // edges per k_bucket block
#define PADMETA 990208  // >= N_EDGES + N_NODES*7 (max padded CSR size)
#define DUMMY ((uint)N_NODES)   // col=N_NODES (zero xl row), gi=0

// k_prep block partition
#define PB_PACKW 64      // 16384/256
#define PB_EMBED 6250    // N_NODES*32/256
#define PB_COUNT 2500    // N_EDGES/256

typedef unsigned int uint;
typedef unsigned short ushort;
typedef __attribute__((ext_vector_type(8))) short bf16x8;   // MFMA A/B frag (4 VGPRs)
typedef __attribute__((ext_vector_type(4))) float f32x4;    // MFMA C/D frag

__device__ inline ushort f2bf(float f) {   // RNE float->bf16 (finite inputs)
    uint u = __float_as_uint(f);
    uint r = (u + 0x7fffu + ((u >> 16) & 1u)) >> 16;
    return (ushort)r;
}
__device__ inline uint packbf(float lo, float hi) {
    return (uint)f2bf(lo) | ((uint)f2bf(hi) << 16);
}
__device__ inline float bflo(uint u) { return __uint_as_float(u << 16); }
__device__ inline float bfhi(uint u) { return __uint_as_float(u & 0xffff0000u); }

// ---------------------------------------------------------------------------
// Fused prep: [0,64) packw (lw+fw2), [64,6314) embed, [6314,8814) edge count,
// [8814] zero the dummy xl row. All sections independent.
__global__ __launch_bounds__(256) void k_prep(const float* __restrict__ lw,
                                              const float* __restrict__ fw2,
                                              uint4* __restrict__ pb,
                                              uint4* __restrict__ pb2,
                                              const int* __restrict__ x,
                                              const float* __restrict__ emb,
                                              ushort* __restrict__ hbf,
                                              const int* __restrict__ row,
                                              int* __restrict__ counts,
                                              ushort* __restrict__ xlb) {
    int b = blockIdx.x, t = threadIdx.x;
    if (b < PB_PACKW) {
        int idx = b * 256 + t;                  // < 16384
        int which = idx >> 13;                  // 0: lw->pb, 1: fw2->pb2
        int rem = idx & 8191;
        int lane = rem & 63;
        int kc = (rem >> 6) & 3;
        int nt = (rem >> 8) & 7;
        int layer = rem >> 11;
        int quad = lane >> 4, nl = lane & 15;
        int n = nt * 16 + nl;
        const float* w = (which ? fw2 : lw) + layer * HIDDEN * HIDDEN;
        uint r[4];
        #pragma unroll
        for (int jj = 0; jj < 4; jj++) {
            int k = kc * 32 + quad * 8 + 2 * jj;
            r[jj] = packbf(w[k * HIDDEN + n], w[(k + 1) * HIDDEN + n]);
        }
        uint4 o; o.x = r[0]; o.y = r[1]; o.z = r[2]; o.w = r[3];
        (which ? pb2 : pb)[rem] = o;
    } else if (b < PB_PACKW + PB_EMBED) {
        int idx = (b - PB_PACKW) * 256 + t;     // over N_NODES*32 float4s
        if (idx < N_NODES * 32) {
            int n = idx >> 5, q = idx & 31;
            float4 v = ((const float4*)emb)[x[n] * 32 + q];
            uint2 p;
            p.x = packbf(v.x, v.y);
            p.y = packbf(v.z, v.w);
            ((uint2*)hbf)[idx] = p;
        }
    } else if (b < PB_PACKW + PB_EMBED + PB_COUNT) {
        int e = (b - PB_PACKW - PB_EMBED) * 256 + t;
        if (e < N_EDGES) atomicAdd(&counts[row[e]], 1);
    } else {
        if (t < 64) ((uint*)(xlb + (size_t)N_NODES * HIDDEN))[t] = 0;
    }
}

// ---------------------------------------------------------------------------
// Fused table build: one block = 64 grid points of one layer.
// rbf -> stage1 (VALU, K=50) -> LDS bf16 -> stage2 MFMA -> ctab bf16 rows.
__global__ __launch_bounds__(256) void k_tab(const float* __restrict__ fw1,
                                             const float* __restrict__ fb1,
                                             const uint4* __restrict__ pb2,
                                             const float* __restrict__ fb2,
                                             ushort* __restrict__ ctab) {
    int layer = blockIdx.x / (TAB / 64);
    int g0 = (blockIdx.x % (TAB / 64)) * 64;
    int t = threadIdx.x;
    __shared__ float rbf[64][NUM_RBF];      // 12.8 KB
    __shared__ ushort hid[64][HIDDEN];      // 16 KB
    for (int idx = t; idx < 64 * NUM_RBF; idx += 256) {
        int gg = idx / NUM_RBF, r = idx % NUM_RBF;
        float d = (CUTOFF * (g0 + gg)) / (float)(TAB - 1);
        float offset = (CUTOFF * r) / (float)(NUM_RBF - 1);
        float delta = CUTOFF / (float)(NUM_RBF - 1);
        float coeff = -0.5f / (delta * delta);
        float tt = d - offset;
        rbf[gg][r] = expf(coeff * tt * tt);
    }
    __syncthreads();
    // stage 1: thread handles channel ch for 32 grid points
    {
        int ch = t & 127;
        int gb = (t >> 7) * 32;             // 0 or 32
        const float* w1 = fw1 + layer * NUM_RBF * HIDDEN;
        float b1 = fb1[layer * HIDDEN + ch];
        float acc[32];
        #pragma unroll
        for (int i = 0; i < 32; i++) acc[i] = b1;
        for (int r = 0; r < NUM_RBF; r++) {
            float w = w1[r * HIDDEN + ch];
            #pragma unroll
            for (int i = 0; i < 32; i++) acc[i] = fmaf(rbf[gb + i][r], w, acc[i]);
        }
        #pragma unroll
        for (int i = 0; i < 32; i++) hid[gb + i][ch] = f2bf(fmaxf(acc[i], 0.0f));
    }
    __syncthreads();
    // stage 2: wave w does MFMA for local rows w*16..w*16+15
    int wave = t >> 6, lane = t & 63;
    int quad = lane >> 4, ml = lane & 15;
    const ushort* arow = &hid[wave * 16 + ml][quad * 8];
    bf16x8 a[4];
    #pragma unroll
    for (int kc = 0; kc < 4; kc++) a[kc] = *(const bf16x8*)(arow + kc * 32);
    const uint4* pb = pb2 + (size_t)layer * 8 * 4 * 64;
    const float* bias = fb2 + layer * HIDDEN;
    int m0 = layer * TAB + g0 + wave * 16;
    #pragma unroll
    for (int nt = 0; nt < 8; nt++) {
        f32x4 acc = {0.f, 0.f, 0.f, 0.f};
        #pragma unroll
        for (int kc = 0; kc < 4; kc++) {
            bf16x8 bfr = *(const bf16x8*)(pb + (nt * 4 + kc) * 64 + lane);
            acc = __builtin_amdgcn_mfma_f32_16x16x32_bf16(a[kc], bfr, acc, 0, 0, 0);
        }
        int col = nt * 16 + ml;
        float bv = bias[col];
        #pragma unroll
        for (int r = 0; r < 4; r++) {
            int rowi = m0 + quad * 4 + r;
            ctab[(size_t)rowi * HIDDEN + col] = f2bf(acc[r] + bv);
        }
    }
}

// ---------------------------------------------------------------------------
// Parallel padded scan (3 kernels, as in R12 — the single-block fusion was a
// 62 us serialization regression in R13).
__global__ void k_scan1(const int* __restrict__ counts, int* __restrict__ partial,
                        int* __restrict__ blocksum) {
    int i = blockIdx.x * 256 + threadIdx.x;
    int c = (i < N_NODES) ? counts[i] : 0;
    int v = (c + 7) & ~7;                              // pad to x8
    int lane = threadIdx.x & 63;
    int wid = threadIdx.x >> 6;
    int s = v;
    #pragma unroll
    for (int off = 1; off < 64; off <<= 1) {
        int t = __shfl_up(s, off, 64);
        if (lane >= off) s += t;
    }
    __shared__ int wsum[4];
    if (lane == 63) wsum[wid] = s;
    __syncthreads();
    int woff = 0;
    for (int w = 0; w < wid; w++) woff += wsum[w];
    int incl = s + woff;
    if (i < N_NODES) partial[i] = incl - v;           // exclusive within block
    if (threadIdx.x == 255) blocksum[blockIdx.x] = incl;
}

// scan of block sums + (merged) graph-boundary binary search.
__global__ void k_scan2(int* __restrict__ blocksum, int nblk,
                        const int* __restrict__ batch, int* __restrict__ gstart,
                        int* __restrict__ padtotal) {
    int tid = threadIdx.x;
    if (tid <= N_GRAPHS) {                 // merged k_bounds
        int lo = 0, hi = N_NODES;
        while (lo < hi) {
            int mid = (lo + hi) >> 1;
            if (batch[mid] < tid) lo = mid + 1; else hi = mid;
        }
        gstart[tid] = lo;
    }
    int v = (tid < nblk) ? blocksum[tid] : 0;
    int lane = tid & 63, wid = tid >> 6;
    int s = v;
    #pragma unroll
    for (int off = 1; off < 64; off <<= 1) {
        int t = __shfl_up(s, off, 64);
        if (lane >= off) s += t;
    }
    __shared__ int wsum[4];
    if (lane == 63) wsum[wid] = s;
    __syncthreads();
    int woff = 0;
    for (int w = 0; w < wid; w++) woff += wsum[w];
    int incl = s + woff;
    if (tid < nblk) blocksum[tid] = incl - v;         // exclusive
    if (tid == nblk - 1) *padtotal = incl;            // total padded edges
}

// Writes padded offsets; seeds bucket cursors at bucket row boundaries.
__global__ void k_scan3(const int* __restrict__ partial, const int* __restrict__ blocksum,
                        const int* __restrict__ padtotal,
                        int* __restrict__ offsets, int* __restrict__ bcur) {
    int i = blockIdx.x * 256 + threadIdx.x;
    if (i < N_NODES) {
        int o = partial[i] + blocksum[blockIdx.x];
        offsets[i] = o;
        if ((i & 255) == 0) bcur[i >> 8] = o;
    }
    if (i == 0) offsets[N_NODES] = *padtotal;
}

// ---------------------------------------------------------------------------
// Bucket sort pass: chunk of CHUNK edges -> LDS histogram/scan/stage ->
// coalesced run writes into per-bucket global spans (8B: packed meta + row).
__global__ __launch_bounds__(256) void k_bucket(const int* __restrict__ row,
                                                const int* __restrict__ col,
                                                const float* __restrict__ eattr,
                                                int* __restrict__ bcur,
                                                uint2* __restrict__ bs) {
    __shared__ uint2 stage[CHUNK];
    __shared__ int hist[256], lscan[256], lcur[256], gbase[256];
    __shared__ int wsum[4];
    int t = threadIdx.x;
    int e0 = blockIdx.x * CHUNK;
    int ne = min(CHUNK, N_EDGES - e0);
    hist[t] = 0;
    __syncthreads();
    for (int i = t; i < ne; i += 256)
        atomicAdd(&hist[row[e0 + i] >> 8], 1);
    __syncthreads();
    int v = hist[t];
    int lane = t & 63, wid = t >> 6;
    int s = v;
    #pragma unroll
    for (int off = 1; off < 64; off <<= 1) {
        int u = __shfl_up(s, off, 64);
        if (lane >= off) s += u;
    }
    if (lane == 63) wsum[wid] = s;
    __syncthreads();
    int woff = 0;
    for (int w = 0; w < wid; w++) woff += wsum[w];
    int excl = s + woff - v;
    lscan[t] = excl;
    lcur[t] = excl;
    if (v > 0) gbase[t] = atomicAdd(&bcur[t], v);   // reserve span in bucket
    __syncthreads();
    for (int i = t; i < ne; i += 256) {
        int e = e0 + i;
        int r = row[e];
        float tt = eattr[e] * ((float)(TAB - 1) / CUTOFF);
        int gi = (int)(tt + 0.5f);
        gi = min(max(gi, 0), TAB - 1);
        int pos = atomicAdd(&lcur[r >> 8], 1);
        uint2 sv;
        sv.x = (uint)col[e] | ((uint)gi << COLBITS);
        sv.y = (uint)r;
        stage[pos] = sv;
    }
    __syncthreads();
    for (int i = t; i < ne; i += 256) {
        uint2 sv = stage[i];
        int b = sv.y >> 8;
        bs[gbase[b] + (i - lscan[b])] = sv;   // coalesced run writes
    }
}

// Fine scatter within each bucket's meta window (single-writer block), then
// fill each node's pad slots [real_end, padded_end) with DUMMY edges.
__global__ __launch_bounds__(256) void k_scatter(const uint2* __restrict__ bs,
                                                 const int* __restrict__ offsets,
                                                 const int* __restrict__ bend,
                                                 uint* __restrict__ meta) {
    int b = blockIdx.x, t = threadIdx.x;
    int r0 = b << 8;
    __shared__ int cur[256];
    int rmax = min(r0 + 256, N_NODES);
    cur[t] = offsets[min(r0 + t, N_NODES)];
    __syncthreads();
    int s = offsets[r0], e = bend[b];       // real edges live in [s, bend)
    for (int i = s + t; i < e; i += 256) {
        uint2 v = bs[i];
        int slot = atomicAdd(&cur[v.y - r0], 1);
        meta[slot] = v.x;
    }
    __syncthreads();
    int node = r0 + t;
    if (node < rmax) {
        int end = offsets[node + 1];
        for (int i = cur[t]; i < end; i++) meta[i] = DUMMY;
    }
}

// ---------------------------------------------------------------------------
// xl = h @ lw + lb via bf16 MFMA. One wave = 16 rows x 128 cols.
__global__ __launch_bounds__(256) void k_xl(const ushort* __restrict__ hbf,
                                            const uint4* __restrict__ pb,
                                            const float* __restrict__ lb,
                                            ushort* __restrict__ xlb) {
    int wave = threadIdx.x >> 6, lane = threadIdx.x & 63;
    int m0 = (blockIdx.x * 4 + wave) * 16;
    if (m0 >= N_NODES) return;
    int quad = lane >> 4, ml = lane & 15;
    const ushort* arow = hbf + (size_t)(m0 + ml) * HIDDEN + quad * 8;
    bf16x8 a[4];
    #pragma unroll
    for (int kc = 0; kc < 4; kc++) a[kc] = *(const bf16x8*)(arow + kc * 32);
    #pragma unroll
    for (int nt = 0; nt < 8; nt++) {
        f32x4 acc = {0.f, 0.f, 0.f, 0.f};
        #pragma unroll
        for (int kc = 0; kc < 4; kc++) {
            bf16x8 b = *(const bf16x8*)(pb + (nt * 4 + kc) * 64 + lane);
            acc = __builtin_amdgcn_mfma_f32_16x16x32_bf16(a[kc], b, acc, 0, 0, 0);
        }
        int col = nt * 16 + ml;
        float bias = lb[col];
        #pragma unroll
        for (int r = 0; r < 4; r++) {
            int row = m0 + quad * 4 + r;
            xlb[(size_t)row * HIDDEN + col] = f2bf(acc[r] + bias);
        }
    }
}

// ---------------------------------------------------------------------------
// Aggregation + residual + LayerNorm, fused. One wave per node.
// Edge lists padded to x8; paired 8-groups keep 32 gathers in flight.
__global__ __launch_bounds__(256) void k_agg(const ushort* __restrict__ xlb,
                                             const uint* __restrict__ meta,
                                             const int* __restrict__ offsets,
                                             const uint* __restrict__ ctab,
                                             const ushort* __restrict__ hb_in,
                                             const float* __restrict__ g,
                                             const float* __restrict__ b,
                                             ushort* __restrict__ hbf_out) {
    int wid = threadIdx.x >> 6;
    int lane = threadIdx.x & 63;
    int n = blockIdx.x * 4 + wid;
    if (n >= N_NODES) return;
    const uint* xl2 = (const uint*)xlb;    // bf16 pair per uint
    float accx = 0.f, accy = 0.f;
    int p0 = offsets[n], p1 = offsets[n + 1];
    int cnt = p1 - p0;                      // multiple of 8
    for (int base = 0; base < cnt; base += 64) {
        int li = p0 + base + lane;
        uint mlv = meta[min(li, PADMETA - 1)];   // coalesced batch load
        int kk = min(64, cnt - base);            // multiple of 8
        int p = 0;
        for (; p + 16 <= kk; p += 16) {          // paired groups: 32 loads in flight
            uint wA[8], xA[8], wB[8], xB[8];
            #pragma unroll
            for (int i = 0; i < 8; i++) {
                uint m = __builtin_amdgcn_readlane(mlv, p + i);
                wA[i] = ctab[(m >> COLBITS) * 64 + lane];
                xA[i] = xl2[(m & CMASK) * 64 + lane];
            }
            #pragma unroll
            for (int i = 0; i < 8; i++) {
                uint m = __builtin_amdgcn_readlane(mlv, p + 8 + i);
                wB[i] = ctab[(m >> COLBITS) * 64 + lane];
                xB[i] = xl2[(m & CMASK) * 64 + lane];
            }
            #pragma unroll
            for (int i = 0; i < 8; i++) {
                accx = fmaf(bflo(wA[i]), bflo(xA[i]), accx);
                accy = fmaf(bfhi(wA[i]), bfhi(xA[i]), accy);
            }
            #pragma unroll
            for (int i = 0; i < 8; i++) {
                accx = fmaf(bflo(wB[i]), bflo(xB[i]), accx);
                accy = fmaf(bfhi(wB[i]), bfhi(xB[i]), accy);
            }
        }
        for (; p < kk; p += 8) {                 // at most one trailing group
            uint wA[8], xA[8];
            #pragma unroll
            for (int i = 0; i < 8; i++) {
                uint m = __builtin_amdgcn_readlane(mlv, p + i);
                wA[i] = ctab[(m >> COLBITS) * 64 + lane];
                xA[i] = xl2[(m & CMASK) * 64 + lane];
            }
            #pragma unroll
            for (int i = 0; i < 8; i++) {
                accx = fmaf(bflo(wA[i]), bflo(xA[i]), accx);
                accy = fmaf(bfhi(wA[i]), bfhi(xA[i]), accy);
            }
        }
    }
    uint hvp = ((const uint*)hb_in)[n * 64 + lane];
    float vx = bflo(hvp) + accx, vy = bfhi(hvp) + accy;
    float s = vx + vy;
    #pragma unroll
    for (int off = 32; off; off >>= 1) s += __shfl_xor(s, off, 64);
    float mu = s * (1.0f / 128.0f);
    float dx = vx - mu, dy = vy - mu;
    float s2 = dx * dx + dy * dy;
    #pragma unroll
    for (int off = 32; off; off >>= 1) s2 += __shfl_xor(s2, off, 64);
    float rstd = rsqrtf(s2 * (1.0f / 128.0f) + 1e-5f);
    float2 gv = ((const float2*)g)[lane];
    float2 bv = ((const float2*)b)[lane];
    float ox = fmaf(dx * rstd, gv.x, bv.x);
    float oy = fmaf(dy * rstd, gv.y, bv.y);
    ((uint*)hbf_out)[n * 64 + lane] = packbf(ox, oy);
}

// ---------------------------------------------------------------------------
// Mean pool, stage 1: PSPLIT blocks per graph write partial sums (bf16 input).
__global__ __launch_bounds__(256) void k_pool_part(const ushort* __restrict__ hbf,
                                                   const int* __restrict__ gstart,
                                                   float* __restrict__ partial) {
    int g = blockIdx.x / PSPLIT;
    int t = blockIdx.x % PSPLIT;
    int jp = threadIdx.x & 63;       // bf16-pair index (2 feats per thread)
    int half = threadIdx.x >> 6;     // 4 node-rows in flight
    int s = gstart[g], e = gstart[g + 1];
    float accx = 0.f, accy = 0.f;
    const uint* h2 = (const uint*)hbf;
    for (int n = s + t * 4 + half; n < e; n += PSPLIT * 4) {
        uint v = h2[n * 64 + jp];
        accx += bflo(v);
        accy += bfhi(v);
    }
    __shared__ float redx[256], redy[256];
    redx[threadIdx.x] = accx;
    redy[threadIdx.x] = accy;
    __syncthreads();
    if (half == 0) {
        float tx = redx[jp] + redx[jp + 64] + redx[jp + 128] + redx[jp + 192];
        float ty = redy[jp] + redy[jp + 64] + redy[jp + 128] + redy[jp + 192];
        float2 o; o.x = tx; o.y = ty;
        ((float2*)partial)[(g * PSPLIT + t) * 64 + jp] = o;
    }
}

// Mean pool, stage 2: reduce PSPLIT partials, divide by count.
__global__ void k_pool_fin(const float* __restrict__ partial,
                           const int* __restrict__ gstart,
                           float* __restrict__ out) {
    int idx = blockIdx.x * 128 + threadIdx.x;   // N_GRAPHS*HIDDEN total
    int g = idx >> 7, j = idx & 127;
    float tot = 0.f;
    #pragma unroll
    for (int t = 0; t < PSPLIT; t++) tot += partial[(g * PSPLIT + t) * HIDDEN + j];
    float c = (float)(gstart[g + 1] - gstart[g]);
    out[idx] = tot / fmaxf(c, 1.0f);
}

// ---------------------------------------------------------------------------
extern "C" void kernel_launch(void* const* d_in, const int* in_sizes, int n_in,
                              void* d_out, int out_size, void* d_ws, size_t ws_size,
                              hipStream_t stream) {
    const int* x = (const int*)d_in[0];
    const int* edge_index = (const int*)d_in[1];
    const int* row = edge_index;               // edge_index[0]
    const int* col = edge_index + N_EDGES;     // edge_index[1]
    const float* eattr = (const float*)d_in[2];
    const int* batch = (const int*)d_in[3];
    const float* emb = (const float*)d_in[4];
    const float* fw1 = (const float*)d_in[5];
    const float* fb1 = (const float*)d_in[6];
    const float* fw2 = (const float*)d_in[7];
    const float* fb2 = (const float*)d_in[8];
    const float* lw = (const float*)d_in[9];
    const float* lb = (const float*)d_in[10];
    const float* ln_g = (const float*)d_in[11];
    const float* ln_b = (const float*)d_in[12];
    float* out = (float*)d_out;

    char* ws = (char*)d_ws;
    size_t off = 0;
    auto alloc = [&](size_t bytes) -> void* {
        void* p = ws + off;
        off = (off + bytes + 255) & ~(size_t)255;
        return p;
    };
    uint* ctab     = (uint*)alloc((size_t)N_LAYERS * TAB * 64 * 4);
    ushort* hbf_a  = (ushort*)alloc((size_t)N_NODES * HIDDEN * 2);
    ushort* hbf_b  = (ushort*)alloc((size_t)N_NODES * HIDDEN * 2);
    ushort* xlb    = (ushort*)alloc((size_t)(N_NODES + 1) * HIDDEN * 2);  // +1 zero row
    uint4* pb      = (uint4*)alloc((size_t)N_LAYERS * 8 * 4 * 64 * 16);
    uint4* pb2     = (uint4*)alloc((size_t)N_LAYERS * 8 * 4 * 64 * 16);
    int* counts    = (int*)alloc((size_t)(N_NODES + 1) * 4);
    int* offsets   = (int*)alloc((size_t)(N_NODES + 1) * 4);
    int* partial   = (int*)alloc((size_t)N_NODES * 4);
    int* blocksum  = (int*)alloc(256 * 4);
    int* bcur      = (int*)alloc(256 * 4);
    int* padtotal  = (int*)alloc(256);
    uint2* bs      = (uint2*)alloc((size_t)PADMETA * 8);
    uint* meta     = (uint*)alloc((size_t)PADMETA * 4);
    int* gstart    = (int*)alloc((size_t)(N_GRAPHS + 1) * 4);
    float* ppart   = (float*)alloc((size_t)N_GRAPHS * PSPLIT * HIDDEN * 4);

    hipMemsetAsync(counts, 0, (size_t)(N_NODES + 1) * 4, stream);

    const int PREP_GRID = PB_PACKW + PB_EMBED + PB_COUNT + 1;   // 8815
    k_prep<<<PREP_GRID, 256, 0, stream>>>(lw, fw2, pb, pb2, x, emb, hbf_a,
                                          row, counts, xlb);
    k_tab<<<N_LAYERS * (TAB / 64), 256, 0, stream>>>(fw1, fb1, pb2, fb2, (ushort*)ctab);
    const int NBLK = (N_NODES + 255) / 256;   // 196
    k_scan1<<<NBLK, 256, 0, stream>>>(counts, partial, blocksum);
    k_scan2<<<1, 256, 0, stream>>>(blocksum, NBLK, batch, gstart, padtotal);
    k_scan3<<<NBLK, 256, 0, stream>>>(partial, blocksum, padtotal, offsets, bcur);
    k_bucket<<<(N_EDGES + CHUNK - 1) / CHUNK, 256, 0, stream>>>(row, col, eattr, bcur, bs);
    k_scatter<<<NBUCK, 256, 0, stream>>>(bs, offsets, bcur, meta);

    ushort* hb_cur = hbf_a; ushort* hb_nxt = hbf_b;
    const int XLBLK = (N_NODES / 16 + 3) / 4;   // 3125 waves -> 782 blocks
    for (int i = 0; i < N_LAYERS; i++) {
        k_xl<<<XLBLK, 256, 0, stream>>>(hb_cur, pb + (size_t)i * 8 * 4 * 64,
                                        lb + i * HIDDEN, xlb);
        k_agg<<<(N_NODES + 3) / 4, 256, 0, stream>>>(xlb, meta, offsets,
                                                     ctab + (size_t)i * TAB * 64,
                                                     hb_cur, ln_g + i * HIDDEN,
                                                     ln_b + i * HIDDEN, hb_nxt);
        ushort* tb = hb_cur; hb_cur = hb_nxt; hb_nxt = tb;
    }
    k_pool_part<<<N_GRAPHS * PSPLIT, 256, 0, stream>>>(hb_cur, gstart, ppart);
    k_pool_fin<<<(N_GRAPHS * HIDDEN + 127) / 128, 128, 0, stream>>>(ppart, gstart, out);
}